// Round 11
// baseline (492.211 us; speedup 1.0000x reference)
//
#include <hip/hip_runtime.h>
#include <math.h>

#define N_NODES 50000
#define N_PAD   50048       // 782 * 64
#define N_EDGES 800000
#define F 128
#define FH 64               // packed bf16x2 words per row
#define B_GRAPHS 64
#define SCAN_NB 49          // ceil(50000 / 1024)
#define N_INT4 12500        // N_NODES / 4
#define NBUCKET 196         // ceil(50000 / 256)
#define SCAT_CHUNK 4096     // edges per phase-A block
#define AGG_NB 12500        // node-blocks per quarter (4 nodes/block)
#define AGGP_NB 1563        // pool node-blocks per quarter (32 nodes/block)

using bf16x8 = __attribute__((ext_vector_type(8))) short;
using f32x4  = __attribute__((ext_vector_type(4))) float;
union U4 { uint4 u; bf16x8 v; };

// ---------------- bf16 helpers ----------------

__device__ __forceinline__ unsigned bf16_rne(float a) {
    unsigned u = __float_as_uint(a);
    u += 0x7fffu + ((u >> 16) & 1u);
    return u >> 16;
}

__device__ __forceinline__ unsigned pack_bf16x2(float a, float b) {
    return bf16_rne(a) | (bf16_rne(b) << 16);
}

__device__ __forceinline__ float2 unpack_bf16x2(unsigned p) {
    return make_float2(__uint_as_float(p << 16),
                       __uint_as_float(p & 0xffff0000u));
}

// split v into hi + lo bf16 words (packed pairwise)
__device__ __forceinline__ void split2(float a, float b, unsigned& hiw, unsigned& low) {
    unsigned ha = bf16_rne(a), hb = bf16_rne(b);
    float ra = a - __uint_as_float(ha << 16);
    float rb = b - __uint_as_float(hb << 16);
    hiw = ha | (hb << 16);
    low = pack_bf16x2(ra, rb);
}

// ---------------- utility ----------------

__global__ __launch_bounds__(256) void zero_i32(int* p, int n) {
    int i = blockIdx.x * blockDim.x + threadIdx.x;
    if (i < n) p[i] = 0;
}

__global__ __launch_bounds__(256) void zero_f32(float* p, int n) {
    int i = blockIdx.x * blockDim.x + threadIdx.x;
    if (i < n) p[i] = 0.f;
}

// ---------------- degree / norm ----------------

__global__ __launch_bounds__(256) void deg_count(const int* __restrict__ dst,
                                                 int* __restrict__ deg) {
    int e = blockIdx.x * blockDim.x + threadIdx.x;
    if (e < N_EDGES) atomicAdd(&deg[dst[e]], 1);
}

__global__ __launch_bounds__(256) void dinv_kernel(const int* __restrict__ deg,
                                                   float* __restrict__ dinv) {
    int i = blockIdx.x * blockDim.x + threadIdx.x;
    if (i < N_NODES) dinv[i] = rsqrtf((float)(deg[i] + 1));  // +1 self-loop
}

// ---------------- CSR build: two-level scan ----------------

__global__ __launch_bounds__(256) void scan1(const int* __restrict__ deg,
                                             int* __restrict__ off,
                                             int* __restrict__ bsum) {
    __shared__ int wsum[4];
    int b = blockIdx.x, t = threadIdx.x;
    int i4 = b * 256 + t;
    int4 v = make_int4(0, 0, 0, 0);
    if (i4 < N_INT4) v = ((const int4*)deg)[i4];
    int s = v.x + v.y + v.z + v.w;
    int lane = t & 63;
    int incl = s;
#pragma unroll
    for (int d = 1; d < 64; d <<= 1) {
        int u = __shfl_up(incl, d, 64);
        if (lane >= d) incl += u;
    }
    int wave = t >> 6;
    if (lane == 63) wsum[wave] = incl;
    __syncthreads();
    int woff = 0;
#pragma unroll
    for (int w = 0; w < 3; ++w) if (w < wave) woff += wsum[w];
    int texcl = woff + incl - s;
    int4 o;
    o.x = texcl;
    o.y = o.x + v.x;
    o.z = o.y + v.y;
    o.w = o.z + v.z;
    if (i4 < N_INT4) ((int4*)off)[i4] = o;
    if (t == 255) bsum[b] = woff + incl;  // block total
}

__global__ __launch_bounds__(64) void scan2(const int* __restrict__ bsum,
                                            int* __restrict__ bexcl,
                                            int* __restrict__ off) {
    int t = threadIdx.x;
    int v = (t < SCAN_NB) ? bsum[t] : 0;
    int incl = v;
#pragma unroll
    for (int d = 1; d < 64; d <<= 1) {
        int u = __shfl_up(incl, d, 64);
        if (t >= d) incl += u;
    }
    if (t < SCAN_NB) bexcl[t] = incl - v;
    if (t == 63) off[N_NODES] = incl;  // grand total (= N_EDGES)
}

__global__ __launch_bounds__(256) void scan3(int* __restrict__ off,
                                             const int* __restrict__ bexcl) {
    int b = blockIdx.x, t = threadIdx.x;
    int i4 = b * 256 + t;
    if (i4 >= N_INT4) return;
    int add = bexcl[b];
    int4 o = ((int4*)off)[i4];
    o.x += add; o.y += add; o.z += add; o.w += add;
    ((int4*)off)[i4] = o;
}

// ---------------- two-phase bucketed scatter ----------------
// pair word = src (bits 0..16, src<50000<2^17) | bucket-local dst (bits 17..24)

__global__ __launch_bounds__(256) void init_bcursor(const int* __restrict__ off,
                                                    int* __restrict__ bcursor) {
    int t = threadIdx.x;
    if (t < NBUCKET) bcursor[t] = off[t << 8];   // t*256 <= 49920 < N_NODES
}

// Phase A: partition edges into bucket-contiguous packed-pair regions.
__global__ __launch_bounds__(256) void scatter_bucket(const int* __restrict__ src,
                                                      const int* __restrict__ dst,
                                                      int* __restrict__ bcursor,
                                                      unsigned* __restrict__ pairs) {
    __shared__ int lcnt[NBUCKET];
    __shared__ int lbase[NBUCKET];
    int t = threadIdx.x;
    int base = blockIdx.x * SCAT_CHUNK;
    for (int i = t; i < NBUCKET; i += 256) lcnt[i] = 0;
    __syncthreads();
#pragma unroll
    for (int i = 0; i < SCAT_CHUNK / 256; ++i) {
        int idx = base + i * 256 + t;
        if (idx < N_EDGES) atomicAdd(&lcnt[dst[idx] >> 8], 1);
    }
    __syncthreads();
    for (int i = t; i < NBUCKET; i += 256) {
        lbase[i] = atomicAdd(&bcursor[i], lcnt[i]);
        lcnt[i] = 0;
    }
    __syncthreads();
#pragma unroll
    for (int i = 0; i < SCAT_CHUNK / 256; ++i) {
        int idx = base + i * 256 + t;
        if (idx < N_EDGES) {
            int s = src[idx], d = dst[idx];
            int b = d >> 8;
            int pos = lbase[b] + atomicAdd(&lcnt[b], 1);
            pairs[pos] = (unsigned)s | ((unsigned)(d & 255) << 17);
        }
    }
}

// Phase B: one block per bucket; place srcs via LDS cursors (no global atomics).
__global__ __launch_bounds__(256) void scatter_place(const unsigned* __restrict__ pairs,
                                                     const int* __restrict__ off,
                                                     int* __restrict__ srcs) {
    __shared__ int lcur[256];
    int b = blockIdx.x;
    int n0 = b << 8;
    int t = threadIdx.x;
    int nodeEnd = n0 + 256; if (nodeEnd > N_NODES) nodeEnd = N_NODES;
    if (n0 + t < N_NODES) lcur[t] = off[n0 + t];
    int start = off[n0];
    int end = off[nodeEnd];
    __syncthreads();
    for (int p = start + t; p < end; p += 256) {
        unsigned pr = pairs[p];
        int pos = atomicAdd(&lcur[pr >> 17], 1);
        srcs[pos] = (int)(pr & 0x1FFFFu);
    }
}

// ---------------- input conversions ----------------
// Quartered layout: buf[q][node][16 words], q = word>>4. One 64B line per row-quarter.

__global__ __launch_bounds__(256) void conv_x(const float* __restrict__ x,
                                              unsigned* __restrict__ Xhi,
                                              unsigned* __restrict__ Xlo) {
    int gid = blockIdx.x * 256 + threadIdx.x;   // 0 .. N*64-1
    if (gid >= N_NODES * FH) return;
    float2 v = *(const float2*)&x[(size_t)gid * 2];
    unsigned hw, lw;
    split2(v.x, v.y, hw, lw);
    int node = gid >> 6, word = gid & 63;
    size_t oidx = ((size_t)(word >> 4) * N_PAD + node) * 16 + (word & 15);
    Xhi[oidx] = hw;
    Xlo[oidx] = lw;
}

// W f32 [128 k][128 n] -> MFMA B-fragment order: Wf[nt][kc][lane][w]
__global__ __launch_bounds__(256) void conv_w(const float* __restrict__ W,
                                              unsigned* __restrict__ Wfh,
                                              unsigned* __restrict__ Wfl) {
    int pos = blockIdx.x * 256 + threadIdx.x;   // 0..2047
    if (pos >= 2048) return;
    int lane = pos & 63;
    int kc = (pos >> 6) & 3;
    int nt = pos >> 8;
    int col = nt * 16 + (lane & 15);
    int kg = lane >> 4;
    uint4 hw, lw;
    unsigned* hp = (unsigned*)&hw;
    unsigned* lp = (unsigned*)&lw;
#pragma unroll
    for (int w = 0; w < 4; ++w) {
        int k0 = kc * 32 + kg * 8 + 2 * w;
        float a = W[(size_t)k0 * F + col];
        float b = W[(size_t)(k0 + 1) * F + col];
        split2(a, b, hp[w], lp[w]);
    }
    ((uint4*)Wfh)[pos] = hw;
    ((uint4*)Wfl)[pos] = lw;
}

// ---------------- MFMA GEMM: Hs[i][c] = bf16( dinv[i] * sum_k X[i][k] W[k][c] ) ----------------
// Quartered X input/Hs output. uint4 g of a row maps to quarter g>>2, local g&3
// (same bytes as the old row-major layout, so LDS/fragment code is unchanged).

__global__ __launch_bounds__(256) void gemm_mfma(const unsigned* __restrict__ Xhi,
                                                 const unsigned* __restrict__ Xlo,
                                                 const unsigned* __restrict__ Wfh,
                                                 const unsigned* __restrict__ Wfl,
                                                 const float* __restrict__ dinv,
                                                 unsigned* __restrict__ Hs) {
    __shared__ uint4 lxh[64 * 16];
    __shared__ uint4 lxl[64 * 16];
    const int tid = threadIdx.x;
    const int m0 = blockIdx.x * 64;

    // stage 64 rows, group-swizzled: group g -> g ^ (row & 7)
#pragma unroll
    for (int i = 0; i < 4; ++i) {
        int idx = i * 256 + tid;          // 0..1023
        int row = idx >> 4;
        int g = idx & 15;
        int gs = g ^ (row & 7);
        size_t qbase = (size_t)(g >> 2) * N_PAD * 4;   // quarter base in uint4s
        lxh[row * 16 + gs] = ((const uint4*)Xhi)[qbase + (size_t)(m0 + row) * 4 + (g & 3)];
        lxl[row * 16 + gs] = ((const uint4*)Xlo)[qbase + (size_t)(m0 + row) * 4 + (g & 3)];
    }
    __syncthreads();

    const int wave = tid >> 6, lane = tid & 63;
    const int lr = lane & 15, kg = lane >> 4;
    const int r = wave * 16 + lr;         // row within block tile

    f32x4 acc[8];
#pragma unroll
    for (int nt = 0; nt < 8; ++nt) acc[nt] = (f32x4){0.f, 0.f, 0.f, 0.f};

#pragma unroll
    for (int kc = 0; kc < 4; ++kc) {
        int gs = (kc * 4 + kg) ^ (r & 7);
        U4 ah, al;
        ah.u = lxh[r * 16 + gs];
        al.u = lxl[r * 16 + gs];
#pragma unroll
        for (int nt = 0; nt < 8; ++nt) {
            U4 bh, bl;
            bh.u = ((const uint4*)Wfh)[(nt * 4 + kc) * 64 + lane];
            bl.u = ((const uint4*)Wfl)[(nt * 4 + kc) * 64 + lane];
            acc[nt] = __builtin_amdgcn_mfma_f32_16x16x32_bf16(ah.v, bh.v, acc[nt], 0, 0, 0);
            acc[nt] = __builtin_amdgcn_mfma_f32_16x16x32_bf16(ah.v, bl.v, acc[nt], 0, 0, 0);
            acc[nt] = __builtin_amdgcn_mfma_f32_16x16x32_bf16(al.v, bh.v, acc[nt], 0, 0, 0);
        }
    }

    // epilogue: D row = m0 + wave*16 + 4*kg + rr, col = nt*16 + lr; quartered store.
#pragma unroll
    for (int rr = 0; rr < 4; ++rr) {
        int row = m0 + wave * 16 + 4 * kg + rr;
        bool ok = row < N_NODES;
        float s = ok ? dinv[row] : 0.f;
#pragma unroll
        for (int nt = 0; nt < 8; ++nt) {
            float v = acc[nt][rr] * s;
            float pv = __shfl_xor(v, 1, 64);    // partner column value
            if (((lane & 1) == 0) && ok) {
                int word = (nt * 16 + lr) >> 1;   // 0..63
                Hs[((size_t)(word >> 4) * N_PAD + row) * 16 + (word & 15)] = pack_bf16x2(v, pv);
            }
        }
    }
}

// ------- quarter edge-sum: neighbor sum + self for one feature-quarter -------
// 4 sub-groups of 16 lanes each take every 4th edge (64B line per gather),
// then shfl-combine. All 64 lanes return the full reduced value.

__device__ __forceinline__ float2 edge_sum_q(const unsigned* __restrict__ HsQ,
                                             const int* __restrict__ off,
                                             const int* __restrict__ srcs,
                                             int node, int sub, int w) {
    float2 acc = make_float2(0.f, 0.f);
    int e0 = off[node], e1 = off[node + 1];
    int e = e0 + sub;
    for (; e + 12 < e1; e += 16) {
        int s0 = srcs[e], s1 = srcs[e + 4], s2 = srcs[e + 8], s3 = srcs[e + 12];
        unsigned p0 = HsQ[(size_t)s0 * 16 + w];
        unsigned p1 = HsQ[(size_t)s1 * 16 + w];
        unsigned p2 = HsQ[(size_t)s2 * 16 + w];
        unsigned p3 = HsQ[(size_t)s3 * 16 + w];
        float2 t0 = unpack_bf16x2(p0), t1 = unpack_bf16x2(p1);
        float2 t2 = unpack_bf16x2(p2), t3 = unpack_bf16x2(p3);
        acc.x += (t0.x + t1.x) + (t2.x + t3.x);
        acc.y += (t0.y + t1.y) + (t2.y + t3.y);
    }
    for (; e < e1; e += 4) {
        float2 t = unpack_bf16x2(HsQ[(size_t)srcs[e] * 16 + w]);
        acc.x += t.x;
        acc.y += t.y;
    }
    acc.x += __shfl_xor(acc.x, 16, 64);
    acc.y += __shfl_xor(acc.y, 16, 64);
    acc.x += __shfl_xor(acc.x, 32, 64);
    acc.y += __shfl_xor(acc.y, 32, 64);
    float2 self = unpack_bf16x2(HsQ[(size_t)node * 16 + w]);
    acc.x += self.x;
    acc.y += self.y;
    return acc;
}

// ------- layers 1,2: quarter-phased aggregate; out = split(relu(dinv*acc + b)) -------

__global__ __launch_bounds__(256) void aggregate_q(const unsigned* __restrict__ HsAll,
                                                   const int* __restrict__ off,
                                                   const int* __restrict__ srcs,
                                                   const float* __restrict__ dinv,
                                                   const float* __restrict__ bias,
                                                   unsigned* __restrict__ XhiAll,
                                                   unsigned* __restrict__ XloAll) {
    int q = blockIdx.x / AGG_NB;          // phase-ordered: all q=0 blocks first
    int nb = blockIdx.x % AGG_NB;
    int node = nb * 4 + (threadIdx.x >> 6);   // always < 50000 (AGG_NB*4 exact)
    int lane = threadIdx.x & 63;
    int sub = lane >> 4, w = lane & 15;
    const unsigned* HsQ = HsAll + (size_t)q * N_PAD * 16;
    float2 acc = edge_sum_q(HsQ, off, srcs, node, sub, w);
    if (sub == 0) {
        float d = dinv[node];
        int f = (q * 16 + w) * 2;
        float o0 = fmaxf(fmaf(d, acc.x, bias[f]), 0.f);
        float o1 = fmaxf(fmaf(d, acc.y, bias[f + 1]), 0.f);
        unsigned hw, lw;
        split2(o0, o1, hw, lw);
        size_t oidx = ((size_t)q * N_PAD + node) * 16 + w;
        XhiAll[oidx] = hw;
        XloAll[oidx] = lw;
    }
}

// ------- layer 3 fused with pool: quarter-phased, run-length flush, sub0 atomics -------

__global__ __launch_bounds__(256) void aggregate_pool_q(const unsigned* __restrict__ HsAll,
                                                        const int* __restrict__ off,
                                                        const int* __restrict__ srcs,
                                                        const float* __restrict__ dinv,
                                                        const float* __restrict__ bias,
                                                        const int* __restrict__ batch,
                                                        float* __restrict__ psums) {
    int q = blockIdx.x / AGGP_NB;
    int nb = blockIdx.x % AGGP_NB;
    int wg = nb * 4 + (threadIdx.x >> 6);
    int lane = threadIdx.x & 63;
    int sub = lane >> 4, w = lane & 15;
    int n0 = wg * 8;
    if (n0 >= N_NODES) return;
    int n1 = n0 + 8;
    if (n1 > N_NODES) n1 = N_NODES;
    const unsigned* HsQ = HsAll + (size_t)q * N_PAD * 16;
    int f = (q * 16 + w) * 2;
    float bx = bias[f], by = bias[f + 1];
    float2 racc = make_float2(0.f, 0.f);
    int cur = batch[n0];
    for (int node = n0; node < n1; ++node) {
        float2 acc = edge_sum_q(HsQ, off, srcs, node, sub, w);
        float d = dinv[node];
        float o0 = fmaf(d, acc.x, bx);   // identical across subs after reduce
        float o1 = fmaf(d, acc.y, by);
        int b = batch[node];
        if (b != cur) {
            if (sub == 0) {
                atomicAdd(&psums[cur * F + f], racc.x);
                atomicAdd(&psums[cur * F + f + 1], racc.y);
            }
            racc = make_float2(0.f, 0.f);
            cur = b;
        }
        racc.x += o0;
        racc.y += o1;
    }
    if (sub == 0) {
        atomicAdd(&psums[cur * F + f], racc.x);
        atomicAdd(&psums[cur * F + f + 1], racc.y);
    }
}

// ---------------- pool finalize: divide by counts (binary search on sorted batch) ----------------

__device__ __forceinline__ int lower_bound_dev(const int* __restrict__ a, int n, int v) {
    int lo = 0, hi = n;
    while (lo < hi) {
        int m = (lo + hi) >> 1;
        if (a[m] < v) lo = m + 1; else hi = m;
    }
    return lo;
}

__global__ __launch_bounds__(128) void pool_finalize(const float* __restrict__ psums,
                                                     const int* __restrict__ batch,
                                                     float* __restrict__ g) {
    int b = blockIdx.x;
    int f = threadIdx.x;
    int lo = lower_bound_dev(batch, N_NODES, b);
    int hi = lower_bound_dev(batch, N_NODES, b + 1);
    float cnt = (float)(hi - lo);
    g[b * F + f] = psums[b * F + f] / fmaxf(cnt, 1.0f);
}

// ---------------- head MLP: out[b] = relu(g fw1 + fb1) fw2 + fb2 ----------------

__global__ __launch_bounds__(64) void head_kernel(const float* __restrict__ g,
                                                  const float* __restrict__ fw1,
                                                  const float* __restrict__ fb1,
                                                  const float* __restrict__ fw2,
                                                  const float* __restrict__ fb2,
                                                  float* __restrict__ out) {
    int b = blockIdx.x;
    int j = threadIdx.x;  // 0..63 hidden unit
    float h = fb1[j];
    for (int k = 0; k < F; ++k)
        h = fmaf(g[b * F + k], fw1[k * 64 + j], h);
    h = fmaxf(h, 0.f) * fw2[j];
#pragma unroll
    for (int w = 32; w >= 1; w >>= 1) h += __shfl_xor(h, w, 64);
    if (j == 0) out[b] = h + fb2[0];
}

// ---------------- launcher ----------------

extern "C" void kernel_launch(void* const* d_in, const int* in_sizes, int n_in,
                              void* d_out, int out_size, void* d_ws, size_t ws_size,
                              hipStream_t stream) {
    const float* x    = (const float*)d_in[0];
    const int* eidx   = (const int*)d_in[1];
    const int* batch  = (const int*)d_in[2];
    const float* W1   = (const float*)d_in[3];
    const float* b1   = (const float*)d_in[4];
    const float* W2   = (const float*)d_in[5];
    const float* b2   = (const float*)d_in[6];
    const float* W3   = (const float*)d_in[7];
    const float* b3   = (const float*)d_in[8];
    const float* fw1  = (const float*)d_in[9];
    const float* fb1  = (const float*)d_in[10];
    const float* fw2  = (const float*)d_in[11];
    const float* fb2  = (const float*)d_in[12];
    float* out        = (float*)d_out;

    const int* src = eidx;            // edge_index[0]
    const int* dst = eidx + N_EDGES;  // edge_index[1]

    // workspace carve-up (total ~43 MB, matches R7's proven footprint)
    char* ws = (char*)d_ws;
    size_t p = 0;
    auto alloc = [&](size_t bytes) -> void* {
        void* r = ws + p;
        p = (p + bytes + 255) & ~(size_t)255;
        return r;
    };
    int*      deg    = (int*)     alloc((size_t)N_NODES * 4);
    float*    dinv   = (float*)   alloc((size_t)N_NODES * 4);
    int*      off    = (int*)     alloc((size_t)(N_NODES + 4) * 4);
    int*      srcs   = (int*)     alloc((size_t)N_EDGES * 4);
    int*      bsum   = (int*)     alloc((size_t)SCAN_NB * 4);
    int*      bexcl  = (int*)     alloc((size_t)SCAN_NB * 4);
    int*      bcursor= (int*)     alloc((size_t)NBUCKET * 4);
    unsigned* XpkHi  = (unsigned*)alloc((size_t)N_PAD * FH * 4);
    unsigned* XpkLo  = (unsigned*)alloc((size_t)N_PAD * FH * 4);
    unsigned* HsPk   = (unsigned*)alloc((size_t)N_PAD * FH * 4);
    unsigned* Wf     = (unsigned*)alloc((size_t)6 * 2048 * 16);   // 3x (hi,lo) fragment-order
    float*    psums  = (float*)   alloc((size_t)B_GRAPHS * F * 4);
    float*    gpool  = (float*)   alloc((size_t)B_GRAPHS * F * 4);
    (void)ws_size;

    // pairs (3.2 MB) aliases HsPk (12.8 MB): pairs is dead before the first
    // gemm_mfma writes HsPk (stream-ordered), so the alias is safe.
    unsigned* pairs = HsPk;

    unsigned* Wf1h = Wf + 0 * 8192;
    unsigned* Wf1l = Wf + 1 * 8192;
    unsigned* Wf2h = Wf + 2 * 8192;
    unsigned* Wf2l = Wf + 3 * 8192;
    unsigned* Wf3h = Wf + 4 * 8192;
    unsigned* Wf3l = Wf + 5 * 8192;

    const int TB = 256;
    const int nblk_N = (N_NODES + TB - 1) / TB;
    const int nblk_E = (N_EDGES + TB - 1) / TB;
    const int gemm_blocks = N_PAD / 64;         // 782
    const int agg_blocks = 4 * AGG_NB;          // 4 quarters x 12500
    const int aggp_blocks = 4 * AGGP_NB;        // 4 quarters x 1563
    const int convx_blocks = (N_NODES * FH + TB - 1) / TB;
    const int scatA_blocks = (N_EDGES + SCAT_CHUNK - 1) / SCAT_CHUNK;  // 196

    // 1. degrees
    zero_i32<<<nblk_N, TB, 0, stream>>>(deg, N_NODES);
    deg_count<<<nblk_E, TB, 0, stream>>>(dst, deg);
    dinv_kernel<<<nblk_N, TB, 0, stream>>>(deg, dinv);

    // 2. CSR: two-level scan + bucketed two-phase scatter
    scan1<<<SCAN_NB, 256, 0, stream>>>(deg, off, bsum);
    scan2<<<1, 64, 0, stream>>>(bsum, bexcl, off);
    scan3<<<SCAN_NB, 256, 0, stream>>>(off, bexcl);
    init_bcursor<<<1, 256, 0, stream>>>(off, bcursor);
    scatter_bucket<<<scatA_blocks, 256, 0, stream>>>(src, dst, bcursor, pairs);
    scatter_place<<<NBUCKET, 256, 0, stream>>>(pairs, off, srcs);

    // 3. conversions
    conv_x<<<convx_blocks, TB, 0, stream>>>(x, XpkHi, XpkLo);
    conv_w<<<8, TB, 0, stream>>>(W1, Wf1h, Wf1l);
    conv_w<<<8, TB, 0, stream>>>(W2, Wf2h, Wf2l);
    conv_w<<<8, TB, 0, stream>>>(W3, Wf3h, Wf3l);
    zero_f32<<<(B_GRAPHS * F + TB - 1) / TB, TB, 0, stream>>>(psums, B_GRAPHS * F);

    // 4. layer 1
    gemm_mfma<<<gemm_blocks, 256, 0, stream>>>(XpkHi, XpkLo, Wf1h, Wf1l, dinv, HsPk);
    aggregate_q<<<agg_blocks, 256, 0, stream>>>(HsPk, off, srcs, dinv, b1, XpkHi, XpkLo);

    // 5. layer 2
    gemm_mfma<<<gemm_blocks, 256, 0, stream>>>(XpkHi, XpkLo, Wf2h, Wf2l, dinv, HsPk);
    aggregate_q<<<agg_blocks, 256, 0, stream>>>(HsPk, off, srcs, dinv, b2, XpkHi, XpkLo);

    // 6. layer 3 fused with pool accumulation
    gemm_mfma<<<gemm_blocks, 256, 0, stream>>>(XpkHi, XpkLo, Wf3h, Wf3l, dinv, HsPk);
    aggregate_pool_q<<<aggp_blocks, 256, 0, stream>>>(HsPk, off, srcs, dinv, b3, batch, psums);

    // 7. finalize mean + head MLP
    pool_finalize<<<B_GRAPHS, 128, 0, stream>>>(psums, batch, gpool);
    head_kernel<<<B_GRAPHS, 64, 0, stream>>>(gpool, fw1, fb1, fw2, fb2, out);
}

// Round 12
// 344.415 us; speedup vs baseline: 1.4291x; 1.4291x over previous
//
#include <hip/hip_runtime.h>
#include <math.h>

#define N_NODES 50000
#define N_PAD   50048       // 782 * 64
#define N_EDGES 800000
#define F 128
#define FH 64               // packed bf16x2 words per row
#define B_GRAPHS 64
#define SCAN_NB 49          // ceil(50000 / 1024)
#define N_INT4 12500        // N_NODES / 4
#define NBUCKET 196         // ceil(50000 / 256)
#define SCAT_CHUNK 4096     // edges per phase-A block

using bf16x8 = __attribute__((ext_vector_type(8))) short;
using f32x4  = __attribute__((ext_vector_type(4))) float;
union U4 { uint4 u; bf16x8 v; };

// ---------------- bf16 helpers ----------------

__device__ __forceinline__ unsigned bf16_rne(float a) {
    unsigned u = __float_as_uint(a);
    u += 0x7fffu + ((u >> 16) & 1u);
    return u >> 16;
}

__device__ __forceinline__ unsigned pack_bf16x2(float a, float b) {
    return bf16_rne(a) | (bf16_rne(b) << 16);
}

__device__ __forceinline__ float2 unpack_bf16x2(unsigned p) {
    return make_float2(__uint_as_float(p << 16),
                       __uint_as_float(p & 0xffff0000u));
}

// split v into hi + lo bf16 words (packed pairwise)
__device__ __forceinline__ void split2(float a, float b, unsigned& hiw, unsigned& low) {
    unsigned ha = bf16_rne(a), hb = bf16_rne(b);
    float ra = a - __uint_as_float(ha << 16);
    float rb = b - __uint_as_float(hb << 16);
    hiw = ha | (hb << 16);
    low = pack_bf16x2(ra, rb);
}

// ---------------- utility ----------------

__global__ __launch_bounds__(256) void zero_i32(int* p, int n) {
    int i = blockIdx.x * blockDim.x + threadIdx.x;
    if (i < n) p[i] = 0;
}

__global__ __launch_bounds__(256) void zero_f32(float* p, int n) {
    int i = blockIdx.x * blockDim.x + threadIdx.x;
    if (i < n) p[i] = 0.f;
}

// ---------------- degree / norm ----------------

__global__ __launch_bounds__(256) void deg_count(const int* __restrict__ dst,
                                                 int* __restrict__ deg) {
    int e = blockIdx.x * blockDim.x + threadIdx.x;
    if (e < N_EDGES) atomicAdd(&deg[dst[e]], 1);
}

__global__ __launch_bounds__(256) void dinv_kernel(const int* __restrict__ deg,
                                                   float* __restrict__ dinv) {
    int i = blockIdx.x * blockDim.x + threadIdx.x;
    if (i < N_NODES) dinv[i] = rsqrtf((float)(deg[i] + 1));  // +1 self-loop
}

// ---------------- CSR build: two-level scan ----------------

__global__ __launch_bounds__(256) void scan1(const int* __restrict__ deg,
                                             int* __restrict__ off,
                                             int* __restrict__ bsum) {
    __shared__ int wsum[4];
    int b = blockIdx.x, t = threadIdx.x;
    int i4 = b * 256 + t;
    int4 v = make_int4(0, 0, 0, 0);
    if (i4 < N_INT4) v = ((const int4*)deg)[i4];
    int s = v.x + v.y + v.z + v.w;
    int lane = t & 63;
    int incl = s;
#pragma unroll
    for (int d = 1; d < 64; d <<= 1) {
        int u = __shfl_up(incl, d, 64);
        if (lane >= d) incl += u;
    }
    int wave = t >> 6;
    if (lane == 63) wsum[wave] = incl;
    __syncthreads();
    int woff = 0;
#pragma unroll
    for (int w = 0; w < 3; ++w) if (w < wave) woff += wsum[w];
    int texcl = woff + incl - s;
    int4 o;
    o.x = texcl;
    o.y = o.x + v.x;
    o.z = o.y + v.y;
    o.w = o.z + v.z;
    if (i4 < N_INT4) ((int4*)off)[i4] = o;
    if (t == 255) bsum[b] = woff + incl;  // block total
}

__global__ __launch_bounds__(64) void scan2(const int* __restrict__ bsum,
                                            int* __restrict__ bexcl,
                                            int* __restrict__ off) {
    int t = threadIdx.x;
    int v = (t < SCAN_NB) ? bsum[t] : 0;
    int incl = v;
#pragma unroll
    for (int d = 1; d < 64; d <<= 1) {
        int u = __shfl_up(incl, d, 64);
        if (t >= d) incl += u;
    }
    if (t < SCAN_NB) bexcl[t] = incl - v;
    if (t == 63) off[N_NODES] = incl;  // grand total (= N_EDGES)
}

__global__ __launch_bounds__(256) void scan3(int* __restrict__ off,
                                             const int* __restrict__ bexcl) {
    int b = blockIdx.x, t = threadIdx.x;
    int i4 = b * 256 + t;
    if (i4 >= N_INT4) return;
    int add = bexcl[b];
    int4 o = ((int4*)off)[i4];
    o.x += add; o.y += add; o.z += add; o.w += add;
    ((int4*)off)[i4] = o;
}

// ---------------- two-phase bucketed scatter ----------------
// pair word = src (bits 0..16, src<50000<2^17) | bucket-local dst (bits 17..24)

__global__ __launch_bounds__(256) void init_bcursor(const int* __restrict__ off,
                                                    int* __restrict__ bcursor) {
    int t = threadIdx.x;
    if (t < NBUCKET) bcursor[t] = off[t << 8];   // t*256 <= 49920 < N_NODES
}

// Phase A: partition edges into bucket-contiguous packed-pair regions.
__global__ __launch_bounds__(256) void scatter_bucket(const int* __restrict__ src,
                                                      const int* __restrict__ dst,
                                                      int* __restrict__ bcursor,
                                                      unsigned* __restrict__ pairs) {
    __shared__ int lcnt[NBUCKET];
    __shared__ int lbase[NBUCKET];
    int t = threadIdx.x;
    int base = blockIdx.x * SCAT_CHUNK;
    for (int i = t; i < NBUCKET; i += 256) lcnt[i] = 0;
    __syncthreads();
#pragma unroll
    for (int i = 0; i < SCAT_CHUNK / 256; ++i) {
        int idx = base + i * 256 + t;
        if (idx < N_EDGES) atomicAdd(&lcnt[dst[idx] >> 8], 1);
    }
    __syncthreads();
    for (int i = t; i < NBUCKET; i += 256) {
        lbase[i] = atomicAdd(&bcursor[i], lcnt[i]);
        lcnt[i] = 0;
    }
    __syncthreads();
#pragma unroll
    for (int i = 0; i < SCAT_CHUNK / 256; ++i) {
        int idx = base + i * 256 + t;
        if (idx < N_EDGES) {
            int s = src[idx], d = dst[idx];
            int b = d >> 8;
            int pos = lbase[b] + atomicAdd(&lcnt[b], 1);
            pairs[pos] = (unsigned)s | ((unsigned)(d & 255) << 17);
        }
    }
}

// Phase B: one block per bucket; place srcs via LDS cursors (no global atomics).
__global__ __launch_bounds__(256) void scatter_place(const unsigned* __restrict__ pairs,
                                                     const int* __restrict__ off,
                                                     int* __restrict__ srcs) {
    __shared__ int lcur[256];
    int b = blockIdx.x;
    int n0 = b << 8;
    int t = threadIdx.x;
    int nodeEnd = n0 + 256; if (nodeEnd > N_NODES) nodeEnd = N_NODES;
    if (n0 + t < N_NODES) lcur[t] = off[n0 + t];
    int start = off[n0];
    int end = off[nodeEnd];
    __syncthreads();
    for (int p = start + t; p < end; p += 256) {
        unsigned pr = pairs[p];
        int pos = atomicAdd(&lcur[pr >> 17], 1);
        srcs[pos] = (int)(pr & 0x1FFFFu);
    }
}

// ---------------- input conversions ----------------

// x f32 [N][128] -> hi/lo packed bf16x2 [N][64] row-major
__global__ __launch_bounds__(256) void conv_x(const float* __restrict__ x,
                                              unsigned* __restrict__ Xhi,
                                              unsigned* __restrict__ Xlo) {
    int gid = blockIdx.x * 256 + threadIdx.x;   // 0 .. N*64-1
    if (gid >= N_NODES * FH) return;
    float2 v = *(const float2*)&x[(size_t)gid * 2];
    unsigned hw, lw;
    split2(v.x, v.y, hw, lw);
    Xhi[gid] = hw;
    Xlo[gid] = lw;
}

// All 3 weight matrices -> MFMA B-fragment order in one launch.
// Wf layout per matrix: Wf[nt][kc][lane][w]; 24 blocks: m = blockIdx.x >> 3.
__global__ __launch_bounds__(256) void conv_w3(const float* __restrict__ W1,
                                               const float* __restrict__ W2,
                                               const float* __restrict__ W3,
                                               unsigned* __restrict__ Wf) {
    int m = blockIdx.x >> 3;                    // 0,1,2
    int pos = (blockIdx.x & 7) * 256 + threadIdx.x;   // 0..2047
    const float* W = (m == 0) ? W1 : (m == 1) ? W2 : W3;
    unsigned* Wfh = Wf + (size_t)(2 * m) * 8192;
    unsigned* Wfl = Wf + (size_t)(2 * m + 1) * 8192;
    int lane = pos & 63;
    int kc = (pos >> 6) & 3;
    int nt = pos >> 8;
    int col = nt * 16 + (lane & 15);
    int kg = lane >> 4;
    uint4 hw, lw;
    unsigned* hp = (unsigned*)&hw;
    unsigned* lp = (unsigned*)&lw;
#pragma unroll
    for (int w = 0; w < 4; ++w) {
        int k0 = kc * 32 + kg * 8 + 2 * w;
        float a = W[(size_t)k0 * F + col];
        float b = W[(size_t)(k0 + 1) * F + col];
        split2(a, b, hp[w], lp[w]);
    }
    ((uint4*)Wfh)[pos] = hw;
    ((uint4*)Wfl)[pos] = lw;
}

// ---------------- MFMA GEMM: Hs[i][c] = bf16( dinv[i] * sum_k X[i][k] W[k][c] ) ----------------

__global__ __launch_bounds__(256) void gemm_mfma(const unsigned* __restrict__ Xhi,
                                                 const unsigned* __restrict__ Xlo,
                                                 const unsigned* __restrict__ Wfh,
                                                 const unsigned* __restrict__ Wfl,
                                                 const float* __restrict__ dinv,
                                                 unsigned* __restrict__ Hs) {
    __shared__ uint4 lxh[64 * 16];
    __shared__ uint4 lxl[64 * 16];
    const int tid = threadIdx.x;
    const int m0 = blockIdx.x * 64;

    // stage 64 rows of Xhi/Xlo, group-swizzled: group g -> g ^ (row & 7)
#pragma unroll
    for (int i = 0; i < 4; ++i) {
        int idx = i * 256 + tid;          // 0..1023
        int row = idx >> 4;
        int g = idx & 15;
        int gs = g ^ (row & 7);
        lxh[row * 16 + gs] = ((const uint4*)Xhi)[(size_t)(m0 + row) * 16 + g];
        lxl[row * 16 + gs] = ((const uint4*)Xlo)[(size_t)(m0 + row) * 16 + g];
    }
    __syncthreads();

    const int wave = tid >> 6, lane = tid & 63;
    const int lr = lane & 15, kg = lane >> 4;
    const int r = wave * 16 + lr;         // row within block tile

    f32x4 acc[8];
#pragma unroll
    for (int nt = 0; nt < 8; ++nt) acc[nt] = (f32x4){0.f, 0.f, 0.f, 0.f};

#pragma unroll
    for (int kc = 0; kc < 4; ++kc) {
        int gs = (kc * 4 + kg) ^ (r & 7);
        U4 ah, al;
        ah.u = lxh[r * 16 + gs];
        al.u = lxl[r * 16 + gs];
#pragma unroll
        for (int nt = 0; nt < 8; ++nt) {
            U4 bh, bl;
            bh.u = ((const uint4*)Wfh)[(nt * 4 + kc) * 64 + lane];
            bl.u = ((const uint4*)Wfl)[(nt * 4 + kc) * 64 + lane];
            acc[nt] = __builtin_amdgcn_mfma_f32_16x16x32_bf16(ah.v, bh.v, acc[nt], 0, 0, 0);
            acc[nt] = __builtin_amdgcn_mfma_f32_16x16x32_bf16(ah.v, bl.v, acc[nt], 0, 0, 0);
            acc[nt] = __builtin_amdgcn_mfma_f32_16x16x32_bf16(al.v, bh.v, acc[nt], 0, 0, 0);
        }
    }

    // epilogue: D row = m0 + wave*16 + 4*kg + rr, col = nt*16 + lr.
#pragma unroll
    for (int rr = 0; rr < 4; ++rr) {
        int row = m0 + wave * 16 + 4 * kg + rr;
        bool ok = row < N_NODES;
        float s = ok ? dinv[row] : 0.f;
#pragma unroll
        for (int nt = 0; nt < 8; ++nt) {
            float v = acc[nt][rr] * s;
            float pv = __shfl_xor(v, 1, 64);    // partner column value
            if (((lane & 1) == 0) && ok) {
                Hs[(size_t)row * FH + ((nt * 16 + lr) >> 1)] = pack_bf16x2(v, pv);
            }
        }
    }
}

// ------- shared edge-sum core: acc = Hs[node] + sum Hs[srcs], packed bf16 rows -------
// 16-deep MLP batch (avg degree = 16), then 4, then scalar tail.

__device__ __forceinline__ float2 edge_sum(const unsigned* __restrict__ Hs,
                                           const int* __restrict__ off,
                                           const int* __restrict__ srcs,
                                           int node, int lane) {
    float2 acc = unpack_bf16x2(Hs[(size_t)node * FH + lane]);  // self term
    int e0 = off[node], e1 = off[node + 1];
    int e = e0;
    for (; e + 15 < e1; e += 16) {
        int si[16];
#pragma unroll
        for (int j = 0; j < 16; ++j) si[j] = srcs[e + j];
        unsigned p[16];
#pragma unroll
        for (int j = 0; j < 16; ++j) p[j] = Hs[(size_t)si[j] * FH + lane];
        float sx = 0.f, sy = 0.f;
#pragma unroll
        for (int j = 0; j < 16; ++j) {
            float2 v = unpack_bf16x2(p[j]);
            sx += v.x;
            sy += v.y;
        }
        acc.x += sx;
        acc.y += sy;
    }
    for (; e + 3 < e1; e += 4) {
        int si[4];
#pragma unroll
        for (int j = 0; j < 4; ++j) si[j] = srcs[e + j];
        unsigned p[4];
#pragma unroll
        for (int j = 0; j < 4; ++j) p[j] = Hs[(size_t)si[j] * FH + lane];
        float2 t0 = unpack_bf16x2(p[0]), t1 = unpack_bf16x2(p[1]);
        float2 t2 = unpack_bf16x2(p[2]), t3 = unpack_bf16x2(p[3]);
        acc.x += (t0.x + t1.x) + (t2.x + t3.x);
        acc.y += (t0.y + t1.y) + (t2.y + t3.y);
    }
    for (; e < e1; ++e) {
        float2 v = unpack_bf16x2(Hs[(size_t)srcs[e] * FH + lane]);
        acc.x += v.x;
        acc.y += v.y;
    }
    return acc;
}

// ------- layers 1,2: Xpk = split( relu(dinv*acc + b) ) -------

__global__ __launch_bounds__(256) void aggregate_bf16(const unsigned* __restrict__ Hs,
                                                      const int* __restrict__ off,
                                                      const int* __restrict__ srcs,
                                                      const float* __restrict__ dinv,
                                                      const float* __restrict__ bias,
                                                      unsigned* __restrict__ Xhi,
                                                      unsigned* __restrict__ Xlo) {
    int node = blockIdx.x * 4 + (threadIdx.x >> 6);
    if (node >= N_NODES) return;
    int lane = threadIdx.x & 63;
    float2 acc = edge_sum(Hs, off, srcs, node, lane);
    float d = dinv[node];
    float o0 = fmaxf(fmaf(d, acc.x, bias[2 * lane]), 0.f);
    float o1 = fmaxf(fmaf(d, acc.y, bias[2 * lane + 1]), 0.f);
    unsigned hw, lw;
    split2(o0, o1, hw, lw);
    Xhi[(size_t)node * FH + lane] = hw;
    Xlo[(size_t)node * FH + lane] = lw;
}

// ------- layer 3 fused with pool: wave owns 8 consecutive nodes, run-length flush -------

__global__ __launch_bounds__(256) void aggregate_pool(const unsigned* __restrict__ Hs,
                                                      const int* __restrict__ off,
                                                      const int* __restrict__ srcs,
                                                      const float* __restrict__ dinv,
                                                      const float* __restrict__ bias,
                                                      const int* __restrict__ batch,
                                                      float* __restrict__ psums) {
    int wg = (blockIdx.x * 256 + threadIdx.x) >> 6;   // global wave id
    int lane = threadIdx.x & 63;
    int n0 = wg * 8;
    if (n0 >= N_NODES) return;
    int n1 = n0 + 8;
    if (n1 > N_NODES) n1 = N_NODES;

    float bx = bias[2 * lane], by = bias[2 * lane + 1];
    float2 racc = make_float2(0.f, 0.f);
    int cur = batch[n0];
    for (int node = n0; node < n1; ++node) {
        float2 acc = edge_sum(Hs, off, srcs, node, lane);
        float d = dinv[node];
        float o0 = fmaf(d, acc.x, bx);
        float o1 = fmaf(d, acc.y, by);
        int b = batch[node];
        if (b != cur) {
            atomicAdd(&psums[cur * F + 2 * lane], racc.x);
            atomicAdd(&psums[cur * F + 2 * lane + 1], racc.y);
            racc = make_float2(0.f, 0.f);
            cur = b;
        }
        racc.x += o0;
        racc.y += o1;
    }
    atomicAdd(&psums[cur * F + 2 * lane], racc.x);
    atomicAdd(&psums[cur * F + 2 * lane + 1], racc.y);
}

// ---------------- pool finalize: divide by counts (binary search on sorted batch) ----------------

__device__ __forceinline__ int lower_bound_dev(const int* __restrict__ a, int n, int v) {
    int lo = 0, hi = n;
    while (lo < hi) {
        int m = (lo + hi) >> 1;
        if (a[m] < v) lo = m + 1; else hi = m;
    }
    return lo;
}

__global__ __launch_bounds__(128) void pool_finalize(const float* __restrict__ psums,
                                                     const int* __restrict__ batch,
                                                     float* __restrict__ g) {
    int b = blockIdx.x;
    int f = threadIdx.x;
    int lo = lower_bound_dev(batch, N_NODES, b);
    int hi = lower_bound_dev(batch, N_NODES, b + 1);
    float cnt = (float)(hi - lo);
    g[b * F + f] = psums[b * F + f] / fmaxf(cnt, 1.0f);
}

// ---------------- head MLP: out[b] = relu(g fw1 + fb1) fw2 + fb2 ----------------

__global__ __launch_bounds__(64) void head_kernel(const float* __restrict__ g,
                                                  const float* __restrict__ fw1,
                                                  const float* __restrict__ fb1,
                                                  const float* __restrict__ fw2,
                                                  const float* __restrict__ fb2,
                                                  float* __restrict__ out) {
    int b = blockIdx.x;
    int j = threadIdx.x;  // 0..63 hidden unit
    float h = fb1[j];
    for (int k = 0; k < F; ++k)
        h = fmaf(g[b * F + k], fw1[k * 64 + j], h);
    h = fmaxf(h, 0.f) * fw2[j];
#pragma unroll
    for (int w = 32; w >= 1; w >>= 1) h += __shfl_xor(h, w, 64);
    if (j == 0) out[b] = h + fb2[0];
}

// ---------------- launcher ----------------

extern "C" void kernel_launch(void* const* d_in, const int* in_sizes, int n_in,
                              void* d_out, int out_size, void* d_ws, size_t ws_size,
                              hipStream_t stream) {
    const float* x    = (const float*)d_in[0];
    const int* eidx   = (const int*)d_in[1];
    const int* batch  = (const int*)d_in[2];
    const float* W1   = (const float*)d_in[3];
    const float* b1   = (const float*)d_in[4];
    const float* W2   = (const float*)d_in[5];
    const float* b2   = (const float*)d_in[6];
    const float* W3   = (const float*)d_in[7];
    const float* b3   = (const float*)d_in[8];
    const float* fw1  = (const float*)d_in[9];
    const float* fb1  = (const float*)d_in[10];
    const float* fw2  = (const float*)d_in[11];
    const float* fb2  = (const float*)d_in[12];
    float* out        = (float*)d_out;

    const int* src = eidx;            // edge_index[0]
    const int* dst = eidx + N_EDGES;  // edge_index[1]

    // workspace carve-up (total ~43 MB, matches R7's proven footprint)
    char* ws = (char*)d_ws;
    size_t p = 0;
    auto alloc = [&](size_t bytes) -> void* {
        void* r = ws + p;
        p = (p + bytes + 255) & ~(size_t)255;
        return r;
    };
    int*      deg    = (int*)     alloc((size_t)N_NODES * 4);
    float*    dinv   = (float*)   alloc((size_t)N_NODES * 4);
    int*      off    = (int*)     alloc((size_t)(N_NODES + 4) * 4);
    int*      srcs   = (int*)     alloc((size_t)N_EDGES * 4);
    int*      bsum   = (int*)     alloc((size_t)SCAN_NB * 4);
    int*      bexcl  = (int*)     alloc((size_t)SCAN_NB * 4);
    int*      bcursor= (int*)     alloc((size_t)NBUCKET * 4);
    unsigned* XpkHi  = (unsigned*)alloc((size_t)N_PAD * FH * 4);
    unsigned* XpkLo  = (unsigned*)alloc((size_t)N_PAD * FH * 4);
    unsigned* HsPk   = (unsigned*)alloc((size_t)N_PAD * FH * 4);
    unsigned* Wf     = (unsigned*)alloc((size_t)6 * 2048 * 16);   // 3x (hi,lo) fragment-order
    float*    psums  = (float*)   alloc((size_t)B_GRAPHS * F * 4);
    float*    gpool  = (float*)   alloc((size_t)B_GRAPHS * F * 4);
    (void)ws_size;

    // pairs (3.2 MB) aliases HsPk (12.8 MB): pairs is dead before the first
    // gemm_mfma writes HsPk (stream-ordered), so the alias is safe.
    unsigned* pairs = HsPk;

    unsigned* Wf1h = Wf + 0 * 8192;
    unsigned* Wf1l = Wf + 1 * 8192;
    unsigned* Wf2h = Wf + 2 * 8192;
    unsigned* Wf2l = Wf + 3 * 8192;
    unsigned* Wf3h = Wf + 4 * 8192;
    unsigned* Wf3l = Wf + 5 * 8192;

    const int TB = 256;
    const int nblk_N = (N_NODES + TB - 1) / TB;
    const int nblk_E = (N_EDGES + TB - 1) / TB;
    const int gemm_blocks = N_PAD / 64;         // 782
    const int agg_blocks = (N_NODES + 3) / 4;   // 12500, exact
    const int aggp_blocks = (6250 + 3) / 4 + 1; // 6250 waves of 8 nodes
    const int convx_blocks = (N_NODES * FH + TB - 1) / TB;
    const int scatA_blocks = (N_EDGES + SCAT_CHUNK - 1) / SCAT_CHUNK;  // 196

    // 1. degrees
    zero_i32<<<nblk_N, TB, 0, stream>>>(deg, N_NODES);
    deg_count<<<nblk_E, TB, 0, stream>>>(dst, deg);
    dinv_kernel<<<nblk_N, TB, 0, stream>>>(deg, dinv);

    // 2. CSR: two-level scan + bucketed two-phase scatter
    scan1<<<SCAN_NB, 256, 0, stream>>>(deg, off, bsum);
    scan2<<<1, 64, 0, stream>>>(bsum, bexcl, off);
    scan3<<<SCAN_NB, 256, 0, stream>>>(off, bexcl);
    init_bcursor<<<1, 256, 0, stream>>>(off, bcursor);
    scatter_bucket<<<scatA_blocks, 256, 0, stream>>>(src, dst, bcursor, pairs);
    scatter_place<<<NBUCKET, 256, 0, stream>>>(pairs, off, srcs);

    // 3. conversions
    conv_x<<<convx_blocks, TB, 0, stream>>>(x, XpkHi, XpkLo);
    conv_w3<<<24, TB, 0, stream>>>(W1, W2, W3, Wf);
    zero_f32<<<(B_GRAPHS * F + TB - 1) / TB, TB, 0, stream>>>(psums, B_GRAPHS * F);

    // 4. layer 1
    gemm_mfma<<<gemm_blocks, 256, 0, stream>>>(XpkHi, XpkLo, Wf1h, Wf1l, dinv, HsPk);
    aggregate_bf16<<<agg_blocks, 256, 0, stream>>>(HsPk, off, srcs, dinv, b1, XpkHi, XpkLo);

    // 5. layer 2
    gemm_mfma<<<gemm_blocks, 256, 0, stream>>>(XpkHi, XpkLo, Wf2h, Wf2l, dinv, HsPk);
    aggregate_bf16<<<agg_blocks, 256, 0, stream>>>(HsPk, off, srcs, dinv, b2, XpkHi, XpkLo);

    // 6. layer 3 fused with pool accumulation
    gemm_mfma<<<gemm_blocks, 256, 0, stream>>>(XpkHi, XpkLo, Wf3h, Wf3l, dinv, HsPk);
    aggregate_pool<<<aggp_blocks, 256, 0, stream>>>(HsPk, off, srcs, dinv, b3, batch, psums);

    // 7. finalize mean + head MLP
    pool_finalize<<<B_GRAPHS, 128, 0, stream>>>(psums, batch, gpool);
    head_kernel<<<B_GRAPHS, 64, 0, stream>>>(gpool, fw1, fb1, fw2, fb2, out);
}

// Round 15
// 335.799 us; speedup vs baseline: 1.4658x; 1.0257x over previous
//
#include <hip/hip_runtime.h>
#include <math.h>

#define N_NODES 50000
#define N_PAD   50048       // 782 * 64
#define N_EDGES 800000
#define F 128
#define FH 64               // packed bf16x2 words per row
#define B_GRAPHS 64
#define SCAN_NB 49          // ceil(50000 / 1024)
#define N_INT4 12500        // N_NODES / 4
#define NBUCKET 196         // ceil(50000 / 256)
#define SCAT_CHUNK 4096     // edges per phase-A block

using bf16x8 = __attribute__((ext_vector_type(8))) short;
using f32x4  = __attribute__((ext_vector_type(4))) float;
union U4 { uint4 u; bf16x8 v; };

// ---------------- bf16 helpers ----------------

__device__ __forceinline__ unsigned bf16_rne(float a) {
    unsigned u = __float_as_uint(a);
    u += 0x7fffu + ((u >> 16) & 1u);
    return u >> 16;
}

__device__ __forceinline__ unsigned pack_bf16x2(float a, float b) {
    return bf16_rne(a) | (bf16_rne(b) << 16);
}

__device__ __forceinline__ float2 unpack_bf16x2(unsigned p) {
    return make_float2(__uint_as_float(p << 16),
                       __uint_as_float(p & 0xffff0000u));
}

// split v into hi + lo bf16 words (packed pairwise)
__device__ __forceinline__ void split2(float a, float b, unsigned& hiw, unsigned& low) {
    unsigned ha = bf16_rne(a), hb = bf16_rne(b);
    float ra = a - __uint_as_float(ha << 16);
    float rb = b - __uint_as_float(hb << 16);
    hiw = ha | (hb << 16);
    low = pack_bf16x2(ra, rb);
}

// ---------------- utility ----------------

__global__ __launch_bounds__(256) void zero_i32(int* p, int n) {
    int i = blockIdx.x * blockDim.x + threadIdx.x;
    if (i < n) p[i] = 0;
}

// ---------------- degree ----------------

__global__ __launch_bounds__(256) void deg_count(const int* __restrict__ dst,
                                                 int* __restrict__ deg) {
    int e = blockIdx.x * blockDim.x + threadIdx.x;
    if (e < N_EDGES) atomicAdd(&deg[dst[e]], 1);
}

// ---------------- CSR build: two-level scan (+ fused dinv / psums-zero / bcursor) ----------------

__global__ __launch_bounds__(256) void scan1(const int* __restrict__ deg,
                                             int* __restrict__ off,
                                             int* __restrict__ bsum,
                                             float* __restrict__ dinv) {
    __shared__ int wsum[4];
    int b = blockIdx.x, t = threadIdx.x;
    int i4 = b * 256 + t;
    int4 v = make_int4(0, 0, 0, 0);
    if (i4 < N_INT4) v = ((const int4*)deg)[i4];
    // fused dinv: deg^{-1/2} with +1 self-loop
    if (i4 < N_INT4) {
        float4 dv;
        dv.x = rsqrtf((float)(v.x + 1));
        dv.y = rsqrtf((float)(v.y + 1));
        dv.z = rsqrtf((float)(v.z + 1));
        dv.w = rsqrtf((float)(v.w + 1));
        ((float4*)dinv)[i4] = dv;
    }
    int s = v.x + v.y + v.z + v.w;
    int lane = t & 63;
    int incl = s;
#pragma unroll
    for (int d = 1; d < 64; d <<= 1) {
        int u = __shfl_up(incl, d, 64);
        if (lane >= d) incl += u;
    }
    int wave = t >> 6;
    if (lane == 63) wsum[wave] = incl;
    __syncthreads();
    int woff = 0;
#pragma unroll
    for (int w = 0; w < 3; ++w) if (w < wave) woff += wsum[w];
    int texcl = woff + incl - s;
    int4 o;
    o.x = texcl;
    o.y = o.x + v.x;
    o.z = o.y + v.y;
    o.w = o.z + v.z;
    if (i4 < N_INT4) ((int4*)off)[i4] = o;
    if (t == 255) bsum[b] = woff + incl;  // block total
}

// 256 threads: wave 0 scans block sums; all threads zero psums (independent).
__global__ __launch_bounds__(256) void scan2(const int* __restrict__ bsum,
                                             int* __restrict__ bexcl,
                                             int* __restrict__ off,
                                             float* __restrict__ psums) {
    int t = threadIdx.x;
    for (int i = t; i < B_GRAPHS * F; i += 256) psums[i] = 0.f;
    if (t < 64) {
        int v = (t < SCAN_NB) ? bsum[t] : 0;
        int incl = v;
#pragma unroll
        for (int d = 1; d < 64; d <<= 1) {
            int u = __shfl_up(incl, d, 64);
            if (t >= d) incl += u;
        }
        if (t < SCAN_NB) bexcl[t] = incl - v;
        if (t == 63) off[N_NODES] = incl;  // grand total (= N_EDGES)
    }
}

// adds block offsets; also emits bucket cursors (final off at 256-node boundaries)
__global__ __launch_bounds__(256) void scan3(int* __restrict__ off,
                                             const int* __restrict__ bexcl,
                                             int* __restrict__ bcursor) {
    int b = blockIdx.x, t = threadIdx.x;
    int i4 = b * 256 + t;
    if (i4 >= N_INT4) return;
    int add = bexcl[b];
    int4 o = ((int4*)off)[i4];
    o.x += add; o.y += add; o.z += add; o.w += add;
    ((int4*)off)[i4] = o;
    int node = i4 << 2;
    if ((node & 255) == 0) bcursor[node >> 8] = o.x;
}

// ---------------- two-phase bucketed scatter ----------------
// pair word = src (bits 0..16, src<50000<2^17) | bucket-local dst (bits 17..24)

// Phase A: partition edges into bucket-contiguous packed-pair regions.
__global__ __launch_bounds__(256) void scatter_bucket(const int* __restrict__ src,
                                                      const int* __restrict__ dst,
                                                      int* __restrict__ bcursor,
                                                      unsigned* __restrict__ pairs) {
    __shared__ int lcnt[NBUCKET];
    __shared__ int lbase[NBUCKET];
    int t = threadIdx.x;
    int base = blockIdx.x * SCAT_CHUNK;
    for (int i = t; i < NBUCKET; i += 256) lcnt[i] = 0;
    __syncthreads();
#pragma unroll
    for (int i = 0; i < SCAT_CHUNK / 256; ++i) {
        int idx = base + i * 256 + t;
        if (idx < N_EDGES) atomicAdd(&lcnt[dst[idx] >> 8], 1);
    }
    __syncthreads();
    for (int i = t; i < NBUCKET; i += 256) {
        lbase[i] = atomicAdd(&bcursor[i], lcnt[i]);
        lcnt[i] = 0;
    }
    __syncthreads();
#pragma unroll
    for (int i = 0; i < SCAT_CHUNK / 256; ++i) {
        int idx = base + i * 256 + t;
        if (idx < N_EDGES) {
            int s = src[idx], d = dst[idx];
            int b = d >> 8;
            int pos = lbase[b] + atomicAdd(&lcnt[b], 1);
            pairs[pos] = (unsigned)s | ((unsigned)(d & 255) << 17);
        }
    }
}

// Phase B: one block per bucket; place srcs via LDS cursors (no global atomics).
__global__ __launch_bounds__(256) void scatter_place(const unsigned* __restrict__ pairs,
                                                     const int* __restrict__ off,
                                                     int* __restrict__ srcs) {
    __shared__ int lcur[256];
    int b = blockIdx.x;
    int n0 = b << 8;
    int t = threadIdx.x;
    int nodeEnd = n0 + 256; if (nodeEnd > N_NODES) nodeEnd = N_NODES;
    if (n0 + t < N_NODES) lcur[t] = off[n0 + t];
    int start = off[n0];
    int end = off[nodeEnd];
    __syncthreads();
    for (int p = start + t; p < end; p += 256) {
        unsigned pr = pairs[p];
        int pos = atomicAdd(&lcur[pr >> 17], 1);
        srcs[pos] = (int)(pr & 0x1FFFFu);
    }
}

// ---------------- input conversions ----------------

// x f32 [N][128] -> hi/lo packed bf16x2 [N][64] row-major
__global__ __launch_bounds__(256) void conv_x(const float* __restrict__ x,
                                              unsigned* __restrict__ Xhi,
                                              unsigned* __restrict__ Xlo) {
    int gid = blockIdx.x * 256 + threadIdx.x;   // 0 .. N*64-1
    if (gid >= N_NODES * FH) return;
    float2 v = *(const float2*)&x[(size_t)gid * 2];
    unsigned hw, lw;
    split2(v.x, v.y, hw, lw);
    Xhi[gid] = hw;
    Xlo[gid] = lw;
}

// All 3 weight matrices -> MFMA B-fragment order in one launch.
// Wf layout per matrix: Wf[nt][kc][lane][w]; 24 blocks: m = blockIdx.x >> 3.
__global__ __launch_bounds__(256) void conv_w3(const float* __restrict__ W1,
                                               const float* __restrict__ W2,
                                               const float* __restrict__ W3,
                                               unsigned* __restrict__ Wf) {
    int m = blockIdx.x >> 3;                    // 0,1,2
    int pos = (blockIdx.x & 7) * 256 + threadIdx.x;   // 0..2047
    const float* W = (m == 0) ? W1 : (m == 1) ? W2 : W3;
    unsigned* Wfh = Wf + (size_t)(2 * m) * 8192;
    unsigned* Wfl = Wf + (size_t)(2 * m + 1) * 8192;
    int lane = pos & 63;
    int kc = (pos >> 6) & 3;
    int nt = pos >> 8;
    int col = nt * 16 + (lane & 15);
    int kg = lane >> 4;
    uint4 hw, lw;
    unsigned* hp = (unsigned*)&hw;
    unsigned* lp = (unsigned*)&lw;
#pragma unroll
    for (int w = 0; w < 4; ++w) {
        int k0 = kc * 32 + kg * 8 + 2 * w;
        float a = W[(size_t)k0 * F + col];
        float b = W[(size_t)(k0 + 1) * F + col];
        split2(a, b, hp[w], lp[w]);
    }
    ((uint4*)Wfh)[pos] = hw;
    ((uint4*)Wfl)[pos] = lw;
}

// ---------------- MFMA GEMM: Hs[i][c] = bf16( dinv[i] * sum_k X[i][k] W[k][c] ) ----------------

__global__ __launch_bounds__(256) void gemm_mfma(const unsigned* __restrict__ Xhi,
                                                 const unsigned* __restrict__ Xlo,
                                                 const unsigned* __restrict__ Wfh,
                                                 const unsigned* __restrict__ Wfl,
                                                 const float* __restrict__ dinv,
                                                 unsigned* __restrict__ Hs) {
    __shared__ uint4 lxh[64 * 16];
    __shared__ uint4 lxl[64 * 16];
    const int tid = threadIdx.x;
    const int m0 = blockIdx.x * 64;

    // stage 64 rows of Xhi/Xlo, group-swizzled: group g -> g ^ (row & 7)
#pragma unroll
    for (int i = 0; i < 4; ++i) {
        int idx = i * 256 + tid;          // 0..1023
        int row = idx >> 4;
        int g = idx & 15;
        int gs = g ^ (row & 7);
        lxh[row * 16 + gs] = ((const uint4*)Xhi)[(size_t)(m0 + row) * 16 + g];
        lxl[row * 16 + gs] = ((const uint4*)Xlo)[(size_t)(m0 + row) * 16 + g];
    }
    __syncthreads();

    const int wave = tid >> 6, lane = tid & 63;
    const int lr = lane & 15, kg = lane >> 4;
    const int r = wave * 16 + lr;         // row within block tile

    f32x4 acc[8];
#pragma unroll
    for (int nt = 0; nt < 8; ++nt) acc[nt] = (f32x4){0.f, 0.f, 0.f, 0.f};

#pragma unroll
    for (int kc = 0; kc < 4; ++kc) {
        int gs = (kc * 4 + kg) ^ (r & 7);
        U4 ah, al;
        ah.u = lxh[r * 16 + gs];
        al.u = lxl[r * 16 + gs];
#pragma unroll
        for (int nt = 0; nt < 8; ++nt) {
            U4 bh, bl;
            bh.u = ((const uint4*)Wfh)[(nt * 4 + kc) * 64 + lane];
            bl.u = ((const uint4*)Wfl)[(nt * 4 + kc) * 64 + lane];
            acc[nt] = __builtin_amdgcn_mfma_f32_16x16x32_bf16(ah.v, bh.v, acc[nt], 0, 0, 0);
            acc[nt] = __builtin_amdgcn_mfma_f32_16x16x32_bf16(ah.v, bl.v, acc[nt], 0, 0, 0);
            acc[nt] = __builtin_amdgcn_mfma_f32_16x16x32_bf16(al.v, bh.v, acc[nt], 0, 0, 0);
        }
    }

    // epilogue: D row = m0 + wave*16 + 4*kg + rr, col = nt*16 + lr.
#pragma unroll
    for (int rr = 0; rr < 4; ++rr) {
        int row = m0 + wave * 16 + 4 * kg + rr;
        bool ok = row < N_NODES;
        float s = ok ? dinv[row] : 0.f;
#pragma unroll
        for (int nt = 0; nt < 8; ++nt) {
            float v = acc[nt][rr] * s;
            float pv = __shfl_xor(v, 1, 64);    // partner column value
            if (((lane & 1) == 0) && ok) {
                Hs[(size_t)row * FH + ((nt * 16 + lr) >> 1)] = pack_bf16x2(v, pv);
            }
        }
    }
}

// ------- shared edge-sum core: acc = Hs[node] + sum Hs[srcs], packed bf16 rows -------
// 16-deep MLP batch (avg degree = 16), then 4, then scalar tail.

__device__ __forceinline__ float2 edge_sum(const unsigned* __restrict__ Hs,
                                           const int* __restrict__ off,
                                           const int* __restrict__ srcs,
                                           int node, int lane) {
    float2 acc = unpack_bf16x2(Hs[(size_t)node * FH + lane]);  // self term
    int e0 = off[node], e1 = off[node + 1];
    int e = e0;
    for (; e + 15 < e1; e += 16) {
        int si[16];
#pragma unroll
        for (int j = 0; j < 16; ++j) si[j] = srcs[e + j];
        unsigned p[16];
#pragma unroll
        for (int j = 0; j < 16; ++j) p[j] = Hs[(size_t)si[j] * FH + lane];
        float sx = 0.f, sy = 0.f;
#pragma unroll
        for (int j = 0; j < 16; ++j) {
            float2 v = unpack_bf16x2(p[j]);
            sx += v.x;
            sy += v.y;
        }
        acc.x += sx;
        acc.y += sy;
    }
    for (; e + 3 < e1; e += 4) {
        int si[4];
#pragma unroll
        for (int j = 0; j < 4; ++j) si[j] = srcs[e + j];
        unsigned p[4];
#pragma unroll
        for (int j = 0; j < 4; ++j) p[j] = Hs[(size_t)si[j] * FH + lane];
        float2 t0 = unpack_bf16x2(p[0]), t1 = unpack_bf16x2(p[1]);
        float2 t2 = unpack_bf16x2(p[2]), t3 = unpack_bf16x2(p[3]);
        acc.x += (t0.x + t1.x) + (t2.x + t3.x);
        acc.y += (t0.y + t1.y) + (t2.y + t3.y);
    }
    for (; e < e1; ++e) {
        float2 v = unpack_bf16x2(Hs[(size_t)srcs[e] * FH + lane]);
        acc.x += v.x;
        acc.y += v.y;
    }
    return acc;
}

// ------- layers 1,2: Xpk = split( relu(dinv*acc + b) ) -------

__global__ __launch_bounds__(256) void aggregate_bf16(const unsigned* __restrict__ Hs,
                                                      const int* __restrict__ off,
                                                      const int* __restrict__ srcs,
                                                      const float* __restrict__ dinv,
                                                      const float* __restrict__ bias,
                                                      unsigned* __restrict__ Xhi,
                                                      unsigned* __restrict__ Xlo) {
    int node = blockIdx.x * 4 + (threadIdx.x >> 6);
    if (node >= N_NODES) return;
    int lane = threadIdx.x & 63;
    float2 acc = edge_sum(Hs, off, srcs, node, lane);
    float d = dinv[node];
    float o0 = fmaxf(fmaf(d, acc.x, bias[2 * lane]), 0.f);
    float o1 = fmaxf(fmaf(d, acc.y, bias[2 * lane + 1]), 0.f);
    unsigned hw, lw;
    split2(o0, o1, hw, lw);
    Xhi[(size_t)node * FH + lane] = hw;
    Xlo[(size_t)node * FH + lane] = lw;
}

// ------- layer 3 fused with pool: wave owns 8 consecutive nodes, run-length flush -------

__global__ __launch_bounds__(256) void aggregate_pool(const unsigned* __restrict__ Hs,
                                                      const int* __restrict__ off,
                                                      const int* __restrict__ srcs,
                                                      const float* __restrict__ dinv,
                                                      const float* __restrict__ bias,
                                                      const int* __restrict__ batch,
                                                      float* __restrict__ psums) {
    int wg = (blockIdx.x * 256 + threadIdx.x) >> 6;   // global wave id
    int lane = threadIdx.x & 63;
    int n0 = wg * 8;
    if (n0 >= N_NODES) return;
    int n1 = n0 + 8;
    if (n1 > N_NODES) n1 = N_NODES;

    float bx = bias[2 * lane], by = bias[2 * lane + 1];
    float2 racc = make_float2(0.f, 0.f);
    int cur = batch[n0];
    for (int node = n0; node < n1; ++node) {
        float2 acc = edge_sum(Hs, off, srcs, node, lane);
        float d = dinv[node];
        float o0 = fmaf(d, acc.x, bx);
        float o1 = fmaf(d, acc.y, by);
        int b = batch[node];
        if (b != cur) {
            atomicAdd(&psums[cur * F + 2 * lane], racc.x);
            atomicAdd(&psums[cur * F + 2 * lane + 1], racc.y);
            racc = make_float2(0.f, 0.f);
            cur = b;
        }
        racc.x += o0;
        racc.y += o1;
    }
    atomicAdd(&psums[cur * F + 2 * lane], racc.x);
    atomicAdd(&psums[cur * F + 2 * lane + 1], racc.y);
}

// ---------------- fused pool-finalize + head MLP ----------------
// block b: 128 threads compute g[f] = psums[b][f]/cnt into LDS, then
// threads 0..63 run: out[b] = relu(g fw1 + fb1) fw2 + fb2.

__device__ __forceinline__ int lower_bound_dev(const int* __restrict__ a, int n, int v) {
    int lo = 0, hi = n;
    while (lo < hi) {
        int m = (lo + hi) >> 1;
        if (a[m] < v) lo = m + 1; else hi = m;
    }
    return lo;
}

__global__ __launch_bounds__(128) void pool_head(const float* __restrict__ psums,
                                                 const int* __restrict__ batch,
                                                 const float* __restrict__ fw1,
                                                 const float* __restrict__ fb1,
                                                 const float* __restrict__ fw2,
                                                 const float* __restrict__ fb2,
                                                 float* __restrict__ out) {
    __shared__ float g[F];
    int b = blockIdx.x;
    int f = threadIdx.x;
    int lo = lower_bound_dev(batch, N_NODES, b);
    int hi = lower_bound_dev(batch, N_NODES, b + 1);
    float cnt = (float)(hi - lo);
    g[f] = psums[b * F + f] / fmaxf(cnt, 1.0f);
    __syncthreads();
    if (f < 64) {
        int j = f;
        float h = fb1[j];
        for (int k = 0; k < F; ++k)
            h = fmaf(g[k], fw1[k * 64 + j], h);
        h = fmaxf(h, 0.f) * fw2[j];
#pragma unroll
        for (int w = 32; w >= 1; w >>= 1) h += __shfl_xor(h, w, 64);
        if (j == 0) out[b] = h + fb2[0];
    }
}

// ---------------- launcher ----------------

extern "C" void kernel_launch(void* const* d_in, const int* in_sizes, int n_in,
                              void* d_out, int out_size, void* d_ws, size_t ws_size,
                              hipStream_t stream) {
    const float* x    = (const float*)d_in[0];
    const int* eidx   = (const int*)d_in[1];
    const int* batch  = (const int*)d_in[2];
    const float* W1   = (const float*)d_in[3];
    const float* b1   = (const float*)d_in[4];
    const float* W2   = (const float*)d_in[5];
    const float* b2   = (const float*)d_in[6];
    const float* W3   = (const float*)d_in[7];
    const float* b3   = (const float*)d_in[8];
    const float* fw1  = (const float*)d_in[9];
    const float* fb1  = (const float*)d_in[10];
    const float* fw2  = (const float*)d_in[11];
    const float* fb2  = (const float*)d_in[12];
    float* out        = (float*)d_out;

    const int* src = eidx;            // edge_index[0]
    const int* dst = eidx + N_EDGES;  // edge_index[1]

    // workspace carve-up (total ~43 MB, matches R7's proven footprint)
    char* ws = (char*)d_ws;
    size_t p = 0;
    auto alloc = [&](size_t bytes) -> void* {
        void* r = ws + p;
        p = (p + bytes + 255) & ~(size_t)255;
        return r;
    };
    int*      deg    = (int*)     alloc((size_t)N_NODES * 4);
    float*    dinv   = (float*)   alloc((size_t)N_NODES * 4);
    int*      off    = (int*)     alloc((size_t)(N_NODES + 4) * 4);
    int*      srcs   = (int*)     alloc((size_t)N_EDGES * 4);
    int*      bsum   = (int*)     alloc((size_t)SCAN_NB * 4);
    int*      bexcl  = (int*)     alloc((size_t)SCAN_NB * 4);
    int*      bcursor= (int*)     alloc((size_t)NBUCKET * 4);
    unsigned* XpkHi  = (unsigned*)alloc((size_t)N_PAD * FH * 4);
    unsigned* XpkLo  = (unsigned*)alloc((size_t)N_PAD * FH * 4);
    unsigned* HsPk   = (unsigned*)alloc((size_t)N_PAD * FH * 4);
    unsigned* Wf     = (unsigned*)alloc((size_t)6 * 2048 * 16);   // 3x (hi,lo) fragment-order
    float*    psums  = (float*)   alloc((size_t)B_GRAPHS * F * 4);
    (void)ws_size;

    // pairs (3.2 MB) aliases HsPk (12.8 MB): pairs is dead before the first
    // gemm_mfma writes HsPk (stream-ordered), so the alias is safe.
    unsigned* pairs = HsPk;

    unsigned* Wf1h = Wf + 0 * 8192;
    unsigned* Wf1l = Wf + 1 * 8192;
    unsigned* Wf2h = Wf + 2 * 8192;
    unsigned* Wf2l = Wf + 3 * 8192;
    unsigned* Wf3h = Wf + 4 * 8192;
    unsigned* Wf3l = Wf + 5 * 8192;

    const int TB = 256;
    const int nblk_N = (N_NODES + TB - 1) / TB;
    const int nblk_E = (N_EDGES + TB - 1) / TB;
    const int gemm_blocks = N_PAD / 64;         // 782
    const int agg_blocks = (N_NODES + 3) / 4;   // 12500, exact
    const int aggp_blocks = (6250 + 3) / 4 + 1; // 6250 waves of 8 nodes
    const int convx_blocks = (N_NODES * FH + TB - 1) / TB;
    const int scatA_blocks = (N_EDGES + SCAT_CHUNK - 1) / SCAT_CHUNK;  // 196

    // 1. degrees
    zero_i32<<<nblk_N, TB, 0, stream>>>(deg, N_NODES);
    deg_count<<<nblk_E, TB, 0, stream>>>(dst, deg);

    // 2. CSR: two-level scan (fused dinv/psums-zero/bcursor) + bucketed scatter
    scan1<<<SCAN_NB, 256, 0, stream>>>(deg, off, bsum, dinv);
    scan2<<<1, 256, 0, stream>>>(bsum, bexcl, off, psums);
    scan3<<<SCAN_NB, 256, 0, stream>>>(off, bexcl, bcursor);
    scatter_bucket<<<scatA_blocks, 256, 0, stream>>>(src, dst, bcursor, pairs);
    scatter_place<<<NBUCKET, 256, 0, stream>>>(pairs, off, srcs);

    // 3. conversions
    conv_x<<<convx_blocks, TB, 0, stream>>>(x, XpkHi, XpkLo);
    conv_w3<<<24, TB, 0, stream>>>(W1, W2, W3, Wf);

    // 4. layer 1
    gemm_mfma<<<gemm_blocks, 256, 0, stream>>>(XpkHi, XpkLo, Wf1h, Wf1l, dinv, HsPk);
    aggregate_bf16<<<agg_blocks, 256, 0, stream>>>(HsPk, off, srcs, dinv, b1, XpkHi, XpkLo);

    // 5. layer 2
    gemm_mfma<<<gemm_blocks, 256, 0, stream>>>(XpkHi, XpkLo, Wf2h, Wf2l, dinv, HsPk);
    aggregate_bf16<<<agg_blocks, 256, 0, stream>>>(HsPk, off, srcs, dinv, b2, XpkHi, XpkLo);

    // 6. layer 3 fused with pool accumulation
    gemm_mfma<<<gemm_blocks, 256, 0, stream>>>(XpkHi, XpkLo, Wf3h, Wf3l, dinv, HsPk);
    aggregate_pool<<<aggp_blocks, 256, 0, stream>>>(HsPk, off, srcs, dinv, b3, batch, psums);

    // 7. fused pool-finalize + head MLP
    pool_head<<<B_GRAPHS, 128, 0, stream>>>(psums, batch, fw1, fb1, fw2, fb2, out);
}